// Round 8
// baseline (130.759 us; speedup 1.0000x reference)
//
#include <hip/hip_runtime.h>
#include <stdint.h>

#define Bb 32
#define Ss 2048
#define Dd 128
#define KVB 64
#define NIT (Ss / KVB)   // 32

typedef __attribute__((ext_vector_type(2))) float f32x2;
typedef __attribute__((ext_vector_type(4))) float f32x4;
typedef __attribute__((ext_vector_type(16))) float f32x16;
typedef __attribute__((ext_vector_type(8))) _Float16 f16x8;
typedef __attribute__((ext_vector_type(2))) __fp16 fp16x2;
typedef __attribute__((ext_vector_type(8))) unsigned short u16x8;
typedef __attribute__((ext_vector_type(4))) unsigned short u16x4;

union F16_8 { u16x8 u; uint32_t w[4]; f16x8 h; };
union F16_4 { u16x4 u; uint32_t w[2]; };

__device__ __forceinline__ uint32_t pk2(float a, float b) {   // packed f32->f16 RTZ
    union { fp16x2 h; uint32_t u; } v;
    v.h = __builtin_amdgcn_cvt_pkrtz(a, b);
    return v.u;
}

// ---------------- P1: per-batch mask scan -> u16 index table (zero-padded) + counts ----------------
__global__ __launch_bounds__(256)
void attn_compact_idx(const int* __restrict__ M, unsigned short* __restrict__ IDXg,
                      int* __restrict__ CNT) {
    __shared__ int scan_s[256];
    const int b = blockIdx.x, tid = threadIdx.x;
    const int* m = M + (size_t)b * Ss + tid * 8;
    int loc[8]; int csum = 0;
    {
        int4 a = *(const int4*)m;
        int4 c = *(const int4*)(m + 4);
        loc[0] = (a.x != 0); loc[1] = (a.y != 0); loc[2] = (a.z != 0); loc[3] = (a.w != 0);
        loc[4] = (c.x != 0); loc[5] = (c.y != 0); loc[6] = (c.z != 0); loc[7] = (c.w != 0);
#pragma unroll
        for (int j = 0; j < 8; ++j) csum += loc[j];
    }
    scan_s[tid] = csum;
    __syncthreads();
    for (int off = 1; off < 256; off <<= 1) {     // Hillis-Steele inclusive scan
        int v = scan_s[tid];
        int u = (tid >= off) ? scan_s[tid - off] : 0;
        __syncthreads();
        scan_s[tid] = v + u;
        __syncthreads();
    }
    const int count = scan_s[255];
    int base = scan_s[tid] - csum;                // exclusive prefix
    unsigned short* idx = IDXg + (size_t)b * Ss;
#pragma unroll
    for (int j = 0; j < 8; ++j)
        if (loc[j]) idx[base++] = (unsigned short)(tid * 8 + j);
    for (int p = count + tid; p < Ss; p += 256) idx[p] = 0;   // pad: safe gather target
    if (tid == 0) CNT[b] = count;
}

// ---------------- main: R5 schedule + LDS index table, direct f32 gather ----------------
__global__ __launch_bounds__(256) __attribute__((amdgpu_waves_per_eu(2, 2)))
void attn_fwd_g(const float* __restrict__ Q,
                const float* __restrict__ K,
                const float* __restrict__ V,
                const unsigned short* __restrict__ IDXg,
                const int* __restrict__ CNT,
                float* __restrict__ O) {
    __shared__ unsigned short K_lds[KVB * 128];   // 16 KB, [key][d] fp16, XOR-swizzled
    __shared__ unsigned short VT_lds[128 * 64];   // 16 KB, [d][key] fp16, XOR-swizzled
    __shared__ float maskadd[KVB];
    __shared__ unsigned short IDX_lds[Ss];        // 4 KB, per-batch compacted indices

    const int tid = threadIdx.x;
    const int w   = tid >> 6;
    const int l   = tid & 63;
    const int q31 = l & 31;
    const int hi  = l >> 5;

    const int bid   = blockIdx.x;
    const int batch = (bid & 7) * 4 + (bid >> 7);   // XCD-aware, bijective
    const int qtile = (bid >> 3) & 15;

    const size_t qrow0  = (size_t)batch * Ss + qtile * 128 + w * 32;
    const size_t kvbase = (size_t)batch * Ss * Dd;

    const int count = CNT[batch];
    const int ntile = (count + KVB - 1) >> 6;

    // index table -> LDS (one u16x8 per thread)
    *(u16x8*)&IDX_lds[tid * 8] = *(const u16x8*)(IDXg + (size_t)batch * Ss + tid * 8);
    __syncthreads();

    // ---- staging geometry ----
    const int krow = tid >> 4;            // K: rows krow+16*it
    const int kcol = (tid & 15) << 3;     // K: 8 floats
    const int vi   = tid & 15;            // V: d-pair base (rows 2vi+p+32j)
    const int vk   = (tid >> 4) << 2;     // V: 4 keys

    f32x4 ka[4], kb[4];                   // K tile in flight
    f32x2 vv[4][4];                       // V tile in flight [j][ko]

    auto issueK = [&](int kv) {
#pragma unroll
        for (int it = 0; it < 4; ++it) {
            const int r = IDX_lds[kv + krow + it * 16];   // gathered active-key row
            const float* s = K + kvbase + (size_t)r * Dd + kcol;
            ka[it] = *(const f32x4*)s;
            kb[it] = *(const f32x4*)(s + 4);
        }
    };
    auto writeK = [&](int kv) {
#pragma unroll
        for (int it = 0; it < 4; ++it) {
            int row = krow + it * 16;
            F16_8 t;
            t.w[0] = pk2(ka[it][0], ka[it][1]);
            t.w[1] = pk2(ka[it][2], ka[it][3]);
            t.w[2] = pk2(kb[it][0], kb[it][1]);
            t.w[3] = pk2(kb[it][2], kb[it][3]);
            *(u16x8*)&K_lds[(row * 128 + kcol) ^ ((row & 7) << 3)] = t.u;
        }
        if (tid < KVB) maskadd[tid] = (kv + tid < count) ? 0.f : -1e30f;
    };
    auto issueV = [&](int kv) {
        int rr[4];
#pragma unroll
        for (int ko = 0; ko < 4; ++ko) rr[ko] = IDX_lds[kv + vk + ko];
#pragma unroll
        for (int j = 0; j < 4; ++j)
#pragma unroll
            for (int ko = 0; ko < 4; ++ko)
                vv[j][ko] = *(const f32x2*)(V + kvbase + (size_t)rr[ko] * Dd + 2 * vi + 32 * j);
    };
    auto writeV = [&]() {
#pragma unroll
        for (int j = 0; j < 4; ++j)
#pragma unroll
            for (int p = 0; p < 2; ++p) {
                int row = 2 * vi + p + 32 * j;           // row&7 varies per lane -> conflict-free
                F16_4 t;
                t.w[0] = pk2(vv[j][0][p], vv[j][1][p]);
                t.w[1] = pk2(vv[j][2][p], vv[j][3][p]);
                *(u16x4*)&VT_lds[row * 64 + (vk ^ ((row & 7) << 3))] = t.u;
            }
    };

    // ones A-fragment (rows 0..7 = 1.0) for MFMA-computed l
    F16_8 ones;
    {
        uint32_t ow = (q31 < 8) ? 0x3C003C00u : 0u;
        ones.w[0] = ow; ones.w[1] = ow; ones.w[2] = ow; ones.w[3] = ow;
    }

    const f32x16 z16 = {0,0,0,0,0,0,0,0,0,0,0,0,0,0,0,0};
    f32x16 acco[4];
#pragma unroll
    for (int dn = 0; dn < 4; ++dn) acco[dn] = z16;
    f32x16 accl = z16;
    float mrun = -1e4f;

    // ---- prologue ----
    const float LOG2E = 1.44269504088896340736f;
    if (ntile > 0) { issueK(0); issueV(0); }
    F16_8 qf[8];
#pragma unroll
    for (int ks = 0; ks < 8; ++ks) {
        const float* s = Q + (qrow0 + q31) * Dd + ks * 16 + hi * 8;
        f32x4 a = *(const f32x4*)s;
        f32x4 b = *(const f32x4*)(s + 4);
        qf[ks].w[0] = pk2(a[0] * LOG2E, a[1] * LOG2E);
        qf[ks].w[1] = pk2(a[2] * LOG2E, a[3] * LOG2E);
        qf[ks].w[2] = pk2(b[0] * LOG2E, b[1] * LOG2E);
        qf[ks].w[3] = pk2(b[2] * LOG2E, b[3] * LOG2E);
    }
    if (ntile > 0) {
        writeK(0); writeV();
        __syncthreads();
    }

    for (int t = 0; t < ntile; ++t) {
        if (t < ntile - 1) issueK((t + 1) * KVB);    // hides under QK+softmax

        // ---- S^T = K · Q^T (log2 units) ----
        f32x16 accs[2];
        accs[0] = z16; accs[1] = z16;
#pragma unroll
        for (int ks = 0; ks < 8; ++ks) {
#pragma unroll
            for (int n = 0; n < 2; ++n) {
                int row = n * 32 + q31;
                F16_8 kf;
                kf.u = *(const u16x8*)&K_lds[(row * 128 + ks * 16 + hi * 8) ^ ((row & 7) << 3)];
                accs[n] = __builtin_amdgcn_mfma_f32_32x32x16_f16(kf.h, qf[ks].h, accs[n], 0, 0, 0);
            }
        }

        // ---- pad-mask: only the final partial tile ----
        if ((t == ntile - 1) && (count & 63)) {
#pragma unroll
            for (int n = 0; n < 2; ++n)
#pragma unroll
                for (int blk = 0; blk < 4; ++blk) {
                    f32x4 md = *(const f32x4*)&maskadd[n * 32 + blk * 8 + 4 * hi];
#pragma unroll
                    for (int r = 0; r < 4; ++r) accs[n][blk * 4 + r] += md[r];
                }
        }

        // ---- max: depth-5 tree ----
        float mx[16];
#pragma unroll
        for (int i = 0; i < 16; ++i) mx[i] = fmaxf(accs[0][i], accs[1][i]);
#pragma unroll
        for (int s = 8; s >= 1; s >>= 1)
#pragma unroll
            for (int i = 0; i < s; ++i) mx[i] = fmaxf(mx[i], mx[i + s]);
        float pmax = fmaxf(mx[0], __shfl_xor(mx[0], 32));

        // ---- online softmax, defer-max; threshold 8 nats = 11.54 log2-units ----
        if (!__all(pmax - mrun <= 11.5409f)) {
            float mnew = fmaxf(mrun, pmax);
            float sc = __builtin_amdgcn_exp2f(mrun - mnew);
#pragma unroll
            for (int dn = 0; dn < 4; ++dn)
#pragma unroll
                for (int i = 0; i < 16; ++i) acco[dn][i] *= sc;
            accl[0] *= sc;
            mrun = mnew;
        }

#pragma unroll
        for (int n = 0; n < 2; ++n)
#pragma unroll
            for (int i = 0; i < 16; ++i) accs[n][i] = __builtin_amdgcn_exp2f(accs[n][i] - mrun);

        // ---- P^T -> B-fragments via permlane32_swap ----
        F16_8 pa[4];
#pragma unroll
        for (int ks = 0; ks < 4; ++ks) {
            int n  = ks >> 1;
            int b4 = (ks & 1) * 8;
            uint32_t x0 = pk2(accs[n][b4 + 0], accs[n][b4 + 1]);
            uint32_t x1 = pk2(accs[n][b4 + 2], accs[n][b4 + 3]);
            uint32_t y0 = pk2(accs[n][b4 + 4], accs[n][b4 + 5]);
            uint32_t y1 = pk2(accs[n][b4 + 6], accs[n][b4 + 7]);
            asm volatile("v_permlane32_swap_b32 %0, %1" : "+v"(x0), "+v"(y0));
            asm volatile("v_permlane32_swap_b32 %0, %1" : "+v"(x1), "+v"(y1));
            pa[ks].w[0] = x0; pa[ks].w[1] = x1; pa[ks].w[2] = y0; pa[ks].w[3] = y1;
        }

        __syncthreads();                       // K_lds + maskadd reads of tile t done
        if (t < ntile - 1) { writeK((t + 1) * KVB); issueV((t + 1) * KVB); }

        // ---- O^T += V^T · P^T ----
#pragma unroll
        for (int dn = 0; dn < 4; ++dn) {
            int row = dn * 32 + q31;
#pragma unroll
            for (int ks = 0; ks < 4; ++ks) {
                F16_8 vf;
                vf.u = *(const u16x8*)&VT_lds[row * 64 + ((ks * 16 + hi * 8) ^ ((row & 7) << 3))];
                acco[dn] = __builtin_amdgcn_mfma_f32_32x32x16_f16(vf.h, pa[ks].h, acco[dn], 0, 0, 0);
            }
        }
#pragma unroll
        for (int ks = 0; ks < 4; ++ks)
            accl = __builtin_amdgcn_mfma_f32_32x32x16_f16(ones.h, pa[ks].h, accl, 0, 0, 0);

        __syncthreads();                       // VT_lds reads of tile t done
        if (t < ntile - 1) writeV();
    }

    // ---- epilogue ----
    float lv   = accl[0];
    float linv = lv > 0.f ? 1.0f / lv : 0.f;   // count==0 -> O=0 (matches reference)
    float* orow = O + (qrow0 + q31) * Dd;
#pragma unroll
    for (int dn = 0; dn < 4; ++dn)
#pragma unroll
        for (int rg = 0; rg < 4; ++rg) {
            f32x4 o;
            o[0] = acco[dn][rg * 4 + 0] * linv;
            o[1] = acco[dn][rg * 4 + 1] * linv;
            o[2] = acco[dn][rg * 4 + 2] * linv;
            o[3] = acco[dn][rg * 4 + 3] * linv;
            *(f32x4*)(orow + dn * 32 + rg * 8 + 4 * hi) = o;
        }
}

// ---------------- fallback: verbatim R5 (used only if workspace missing) ----------------
__global__ __launch_bounds__(256) __attribute__((amdgpu_waves_per_eu(2, 2)))
void attn_fwd(const float* __restrict__ Q,
              const float* __restrict__ K,
              const float* __restrict__ V,
              const int* __restrict__ M,
              float* __restrict__ O) {
    __shared__ unsigned short K_lds[KVB * 128];
    __shared__ unsigned short VT_lds[128 * 64];
    __shared__ float maskadd[KVB];

    const int tid = threadIdx.x;
    const int w   = tid >> 6;
    const int l   = tid & 63;
    const int q31 = l & 31;
    const int hi  = l >> 5;

    const int bid   = blockIdx.x;
    const int batch = (bid & 7) * 4 + (bid >> 7);
    const int qtile = (bid >> 3) & 15;

    const size_t qrow0  = (size_t)batch * Ss + qtile * 128 + w * 32;
    const size_t kvbase = (size_t)batch * Ss * Dd;
    const size_t mbase  = (size_t)batch * Ss;

    const int krow = tid >> 4;
    const int kcol = (tid & 15) << 3;
    const int vi   = tid & 15;
    const int vk   = (tid >> 4) << 2;

    f32x4 ka[4], kb[4];
    f32x2 vv[4][4];
    int mld = 0;

    auto issueK = [&](int kv) {
#pragma unroll
        for (int it = 0; it < 4; ++it) {
            const float* s = K + kvbase + (size_t)(kv + krow + it * 16) * Dd + kcol;
            ka[it] = *(const f32x4*)s;
            kb[it] = *(const f32x4*)(s + 4);
        }
        if (tid < KVB) mld = M[mbase + kv + tid];
    };
    auto writeK = [&]() {
#pragma unroll
        for (int it = 0; it < 4; ++it) {
            int row = krow + it * 16;
            F16_8 t;
            t.w[0] = pk2(ka[it][0], ka[it][1]);
            t.w[1] = pk2(ka[it][2], ka[it][3]);
            t.w[2] = pk2(kb[it][0], kb[it][1]);
            t.w[3] = pk2(kb[it][2], kb[it][3]);
            *(u16x8*)&K_lds[(row * 128 + kcol) ^ ((row & 7) << 3)] = t.u;
        }
        if (tid < KVB) maskadd[tid] = mld ? 0.f : -1e30f;
    };
    auto issueV = [&](int kv) {
#pragma unroll
        for (int j = 0; j < 4; ++j)
#pragma unroll
            for (int ko = 0; ko < 4; ++ko)
                vv[j][ko] = *(const f32x2*)(V + kvbase + (size_t)(kv + vk + ko) * Dd + 2 * vi + 32 * j);
    };
    auto writeV = [&]() {
#pragma unroll
        for (int j = 0; j < 4; ++j)
#pragma unroll
            for (int p = 0; p < 2; ++p) {
                int row = 2 * vi + p + 32 * j;
                F16_4 t;
                t.w[0] = pk2(vv[j][0][p], vv[j][1][p]);
                t.w[1] = pk2(vv[j][2][p], vv[j][3][p]);
                *(u16x4*)&VT_lds[row * 64 + (vk ^ ((row & 7) << 3))] = t.u;
            }
    };

    F16_8 ones;
    {
        uint32_t ow = (q31 < 8) ? 0x3C003C00u : 0u;
        ones.w[0] = ow; ones.w[1] = ow; ones.w[2] = ow; ones.w[3] = ow;
    }

    const f32x16 z16 = {0,0,0,0,0,0,0,0,0,0,0,0,0,0,0,0};
    f32x16 acco[4];
#pragma unroll
    for (int dn = 0; dn < 4; ++dn) acco[dn] = z16;
    f32x16 accl = z16;
    float mrun = -1e4f;

    const float LOG2E = 1.44269504088896340736f;
    issueK(0); issueV(0);
    F16_8 qf[8];
#pragma unroll
    for (int ks = 0; ks < 8; ++ks) {
        const float* s = Q + (qrow0 + q31) * Dd + ks * 16 + hi * 8;
        f32x4 a = *(const f32x4*)s;
        f32x4 b = *(const f32x4*)(s + 4);
        qf[ks].w[0] = pk2(a[0] * LOG2E, a[1] * LOG2E);
        qf[ks].w[1] = pk2(a[2] * LOG2E, a[3] * LOG2E);
        qf[ks].w[2] = pk2(b[0] * LOG2E, b[1] * LOG2E);
        qf[ks].w[3] = pk2(b[2] * LOG2E, b[3] * LOG2E);
    }
    writeK(); writeV();
    __syncthreads();

    for (int t = 0; t < NIT; ++t) {
        if (t < NIT - 1) issueK((t + 1) * KVB);

        f32x16 accs[2];
        accs[0] = z16; accs[1] = z16;
#pragma unroll
        for (int ks = 0; ks < 8; ++ks) {
#pragma unroll
            for (int n = 0; n < 2; ++n) {
                int row = n * 32 + q31;
                F16_8 kf;
                kf.u = *(const u16x8*)&K_lds[(row * 128 + ks * 16 + hi * 8) ^ ((row & 7) << 3)];
                accs[n] = __builtin_amdgcn_mfma_f32_32x32x16_f16(kf.h, qf[ks].h, accs[n], 0, 0, 0);
            }
        }

#pragma unroll
        for (int n = 0; n < 2; ++n)
#pragma unroll
            for (int blk = 0; blk < 4; ++blk) {
                f32x4 md = *(const f32x4*)&maskadd[n * 32 + blk * 8 + 4 * hi];
#pragma unroll
                for (int r = 0; r < 4; ++r) accs[n][blk * 4 + r] += md[r];
            }

        float mx[16];
#pragma unroll
        for (int i = 0; i < 16; ++i) mx[i] = fmaxf(accs[0][i], accs[1][i]);
#pragma unroll
        for (int s = 8; s >= 1; s >>= 1)
#pragma unroll
            for (int i = 0; i < s; ++i) mx[i] = fmaxf(mx[i], mx[i + s]);
        float pmax = fmaxf(mx[0], __shfl_xor(mx[0], 32));

        if (!__all(pmax - mrun <= 11.5409f)) {
            float mnew = fmaxf(mrun, pmax);
            float sc = __builtin_amdgcn_exp2f(mrun - mnew);
#pragma unroll
            for (int dn = 0; dn < 4; ++dn)
#pragma unroll
                for (int i = 0; i < 16; ++i) acco[dn][i] *= sc;
            accl[0] *= sc;
            mrun = mnew;
        }

#pragma unroll
        for (int n = 0; n < 2; ++n)
#pragma unroll
            for (int i = 0; i < 16; ++i) accs[n][i] = __builtin_amdgcn_exp2f(accs[n][i] - mrun);

        F16_8 pa[4];
#pragma unroll
        for (int ks = 0; ks < 4; ++ks) {
            int n  = ks >> 1;
            int b4 = (ks & 1) * 8;
            uint32_t x0 = pk2(accs[n][b4 + 0], accs[n][b4 + 1]);
            uint32_t x1 = pk2(accs[n][b4 + 2], accs[n][b4 + 3]);
            uint32_t y0 = pk2(accs[n][b4 + 4], accs[n][b4 + 5]);
            uint32_t y1 = pk2(accs[n][b4 + 6], accs[n][b4 + 7]);
            asm volatile("v_permlane32_swap_b32 %0, %1" : "+v"(x0), "+v"(y0));
            asm volatile("v_permlane32_swap_b32 %0, %1" : "+v"(x1), "+v"(y1));
            pa[ks].w[0] = x0; pa[ks].w[1] = x1; pa[ks].w[2] = y0; pa[ks].w[3] = y1;
        }

        __syncthreads();
        if (t < NIT - 1) { writeK(); issueV((t + 1) * KVB); }

#pragma unroll
        for (int dn = 0; dn < 4; ++dn) {
            int row = dn * 32 + q31;
#pragma unroll
            for (int ks = 0; ks < 4; ++ks) {
                F16_8 vf;
                vf.u = *(const u16x8*)&VT_lds[row * 64 + ((ks * 16 + hi * 8) ^ ((row & 7) << 3))];
                acco[dn] = __builtin_amdgcn_mfma_f32_32x32x16_f16(vf.h, pa[ks].h, acco[dn], 0, 0, 0);
            }
        }
#pragma unroll
        for (int ks = 0; ks < 4; ++ks)
            accl = __builtin_amdgcn_mfma_f32_32x32x16_f16(ones.h, pa[ks].h, accl, 0, 0, 0);

        __syncthreads();
        if (t < NIT - 1) writeV();
    }

    float lv   = accl[0];
    float linv = lv > 0.f ? 1.0f / lv : 0.f;
    float* orow = O + (qrow0 + q31) * Dd;
#pragma unroll
    for (int dn = 0; dn < 4; ++dn)
#pragma unroll
        for (int rg = 0; rg < 4; ++rg) {
            f32x4 o;
            o[0] = acco[dn][rg * 4 + 0] * linv;
            o[1] = acco[dn][rg * 4 + 1] * linv;
            o[2] = acco[dn][rg * 4 + 2] * linv;
            o[3] = acco[dn][rg * 4 + 3] * linv;
            *(f32x4*)(orow + dn * 32 + rg * 8 + 4 * hi) = o;
        }
}

extern "C" void kernel_launch(void* const* d_in, const int* in_sizes, int n_in,
                              void* d_out, int out_size, void* d_ws, size_t ws_size,
                              hipStream_t stream) {
    const float* Q = (const float*)d_in[0];
    const float* K = (const float*)d_in[1];
    const float* V = (const float*)d_in[2];
    const int*   M = (const int*)d_in[3];
    float* O = (float*)d_out;

    const size_t need = (size_t)Bb * Ss * 2 + (size_t)Bb * 4;   // u16 idx + counts

    if (d_ws != nullptr && ws_size >= need) {
        unsigned short* IDXg = (unsigned short*)d_ws;
        int*            CNT  = (int*)(IDXg + (size_t)Bb * Ss);
        attn_compact_idx<<<dim3(Bb), dim3(256), 0, stream>>>(M, IDXg, CNT);
        attn_fwd_g<<<dim3(Bb * (Ss / 128)), dim3(256), 0, stream>>>(Q, K, V, IDXg, CNT, O);
    } else {
        attn_fwd<<<dim3(Bb * (Ss / 128)), dim3(256), 0, stream>>>(Q, K, V, M, O);
    }
}

// Round 9
// 69.610 us; speedup vs baseline: 1.8785x; 1.8785x over previous
//
#include <hip/hip_runtime.h>
#include <stdint.h>

#define Bb 32
#define Ss 2048
#define Dd 128
#define KVB 64
#define NIT (Ss / KVB)   // 32

typedef __attribute__((ext_vector_type(2))) float f32x2;
typedef __attribute__((ext_vector_type(4))) float f32x4;
typedef __attribute__((ext_vector_type(16))) float f32x16;
typedef __attribute__((ext_vector_type(8))) _Float16 f16x8;
typedef __attribute__((ext_vector_type(2))) __fp16 fp16x2;
typedef __attribute__((ext_vector_type(8))) unsigned short u16x8;
typedef __attribute__((ext_vector_type(4))) unsigned short u16x4;

union F16_8 { u16x8 u; uint32_t w[4]; f16x8 h; };
union F16_4 { u16x4 u; uint32_t w[2]; };

__device__ __forceinline__ uint32_t pk2(float a, float b) {   // packed f32->f16 RTZ
    union { fp16x2 h; uint32_t u; } v;
    v.h = __builtin_amdgcn_cvt_pkrtz(a, b);
    return v.u;
}

// ---------------- prep (fused P1+P2): per-batch scan + gather-compact K,V -> fp16 ----------------
__global__ __launch_bounds__(256)
void attn_prep(const float* __restrict__ K, const float* __restrict__ V,
               const int* __restrict__ M,
               unsigned short* __restrict__ Kc, unsigned short* __restrict__ Vc,
               int* __restrict__ CNT) {
    __shared__ int scan_s[256];
    __shared__ unsigned short idx_l[Ss];
    const int b = blockIdx.x >> 5, chunk = blockIdx.x & 31;
    const int tid = threadIdx.x;

    // ---- redundant per-block scan of this batch's mask (8 KB, L2-hot) ----
    const int* m = M + (size_t)b * Ss + tid * 8;
    int loc[8]; int csum = 0;
    {
        int4 a = *(const int4*)m;
        int4 c = *(const int4*)(m + 4);
        loc[0] = (a.x != 0); loc[1] = (a.y != 0); loc[2] = (a.z != 0); loc[3] = (a.w != 0);
        loc[4] = (c.x != 0); loc[5] = (c.y != 0); loc[6] = (c.z != 0); loc[7] = (c.w != 0);
#pragma unroll
        for (int j = 0; j < 8; ++j) csum += loc[j];
    }
    scan_s[tid] = csum;
    __syncthreads();
    for (int off = 1; off < 256; off <<= 1) {     // Hillis-Steele inclusive scan
        int v = scan_s[tid];
        int u = (tid >= off) ? scan_s[tid - off] : 0;
        __syncthreads();
        scan_s[tid] = v + u;
        __syncthreads();
    }
    const int count = scan_s[255];
    {
        int base = scan_s[tid] - csum;            // exclusive prefix
#pragma unroll
        for (int j = 0; j < 8; ++j)
            if (loc[j]) idx_l[base++] = (unsigned short)(tid * 8 + j);
    }
    __syncthreads();
    if (chunk == 0 && tid == 0) CNT[b] = count;

    const int ntpad = ((count + 63) >> 6) << 6;
    const int p0 = chunk * 64;
    if (p0 >= ntpad) return;

    const int rsub = tid >> 4;              // 16 rows in parallel
    const int colh = (tid & 15) * 8;        // 8 elems
    const size_t gbase = (size_t)b * Ss * Dd;
#pragma unroll
    for (int pass = 0; pass < 2; ++pass) {
        const float* src = pass ? V : K;
        unsigned short* dst = pass ? Vc : Kc;
#pragma unroll
        for (int it = 0; it < 4; ++it) {
            int s = p0 + rsub + it * 16;
            if (s >= ntpad) continue;
            F16_8 t;
            if (s < count) {
                const float* sp = src + gbase + (size_t)idx_l[s] * Dd + colh;
                f32x4 x = *(const f32x4*)sp;
                f32x4 y = *(const f32x4*)(sp + 4);
                t.w[0] = pk2(x[0], x[1]); t.w[1] = pk2(x[2], x[3]);
                t.w[2] = pk2(y[0], y[1]); t.w[3] = pk2(y[2], y[3]);
            } else {
                t.w[0] = 0u; t.w[1] = 0u; t.w[2] = 0u; t.w[3] = 0u;   // pad rows zeroed
            }
            *(u16x8*)(dst + gbase + (size_t)s * Dd + colh) = t.u;
        }
    }
}

// ---------------- main: dense fp16 KV, K via global_load_lds, K+V dbuf, ONE barrier/tile ----------------
__global__ __launch_bounds__(256) __attribute__((amdgpu_waves_per_eu(2, 2)))
void attn_fwd_d(const float* __restrict__ Q,
                const unsigned short* __restrict__ Kc,
                const unsigned short* __restrict__ Vc,
                const int* __restrict__ CNT,
                float* __restrict__ O) {
    __shared__ unsigned short K_lds[2][KVB * 128];   // 2x16 KB, [key][d] fp16, XOR-swizzled
    __shared__ unsigned short VT_lds[2][128 * 64];   // 2x16 KB, [d][key] fp16, XOR-swizzled
    __shared__ float maskadd[KVB];

    const int tid = threadIdx.x;
    const int w   = tid >> 6;
    const int l   = tid & 63;
    const int q31 = l & 31;
    const int hi  = l >> 5;

    const int bid   = blockIdx.x;
    const int batch = (bid & 7) * 4 + (bid >> 7);   // XCD-aware, bijective
    const int qtile = (bid >> 3) & 15;

    const size_t qrow0 = (size_t)batch * Ss + qtile * 128 + w * 32;
    const size_t kvb16 = (size_t)batch * Ss * Dd;   // u16 elems

    const int count = CNT[batch];
    const int ntile = (count + KVB - 1) >> 6;

    // ---- K staging: async global->LDS, linear dest, inverse-swizzled SOURCE (T21) ----
    // issue it covers rows [it*16, it*16+16); thread: row = it*16 + tid/16, chunk s = tid%15&...
    const int grow = tid >> 4;          // 0..15 within issue
    const int gs   = tid & 15;          // 16B chunk within row
    auto gloadK = [&](int bf, int kv) {
#pragma unroll
        for (int it = 0; it < 4; ++it) {
            const int r = it * 16 + grow;
            const unsigned short* src = Kc + kvb16 + (size_t)(kv + r) * Dd + ((gs ^ (r & 7)) << 3);
            void* dst = (char*)(&K_lds[bf][0]) + it * 4096 + w * 1024;   // wave-uniform base
            __builtin_amdgcn_global_load_lds(
                (const __attribute__((address_space(1))) uint32_t*)src,
                (__attribute__((address_space(3))) uint32_t*)dst, 16, 0, 0);
        }
    };

    // ---- V staging (register path: transpose repack) ----
    const int vi = tid & 15;            // d-pair base (rows 2vi+p+32j)
    const int vk = (tid >> 4) << 2;     // 4 keys
    uint32_t vv[4][4];                  // V tile in flight [j][ko], 16 VGPR

    auto issueV = [&](int kv) {
#pragma unroll
        for (int j = 0; j < 4; ++j)
#pragma unroll
            for (int ko = 0; ko < 4; ++ko)
                vv[j][ko] = *(const uint32_t*)(Vc + kvb16 + (size_t)(kv + vk + ko) * Dd + 2 * vi + 32 * j);
    };
    auto writeV = [&](int bf) {
#pragma unroll
        for (int j = 0; j < 4; ++j)
#pragma unroll
            for (int p = 0; p < 2; ++p) {
                int row = 2 * vi + p + 32 * j;           // row&7 varies per lane -> conflict-free
                F16_4 t;
                if (p == 0) {
                    t.w[0] = (vv[j][0] & 0xffffu) | (vv[j][1] << 16);
                    t.w[1] = (vv[j][2] & 0xffffu) | (vv[j][3] << 16);
                } else {
                    t.w[0] = (vv[j][0] >> 16) | (vv[j][1] & 0xffff0000u);
                    t.w[1] = (vv[j][2] >> 16) | (vv[j][3] & 0xffff0000u);
                }
                *(u16x4*)&VT_lds[bf][row * 64 + (vk ^ ((row & 7) << 3))] = t.u;
            }
    };

    // ones A-fragment (rows 0..7 = 1.0) for MFMA-computed l
    F16_8 ones;
    {
        uint32_t ow = (q31 < 8) ? 0x3C003C00u : 0u;
        ones.w[0] = ow; ones.w[1] = ow; ones.w[2] = ow; ones.w[3] = ow;
    }

    const f32x16 z16 = {0,0,0,0,0,0,0,0,0,0,0,0,0,0,0,0};
    f32x16 acco[4];
#pragma unroll
    for (int dn = 0; dn < 4; ++dn) acco[dn] = z16;
    f32x16 accl = z16;
    float mrun = -1e4f;

    // ---- prologue ----
    const float LOG2E = 1.44269504088896340736f;
    if (ntile > 0) { gloadK(0, 0); issueV(0); }
    if (tid < KVB) maskadd[tid] = ((ntile - 1) * KVB + tid < count) ? 0.f : -1e30f;  // static
    F16_8 qf[8];
#pragma unroll
    for (int ks = 0; ks < 8; ++ks) {
        const float* s = Q + (qrow0 + q31) * Dd + ks * 16 + hi * 8;
        f32x4 a = *(const f32x4*)s;
        f32x4 b = *(const f32x4*)(s + 4);
        qf[ks].w[0] = pk2(a[0] * LOG2E, a[1] * LOG2E);
        qf[ks].w[1] = pk2(a[2] * LOG2E, a[3] * LOG2E);
        qf[ks].w[2] = pk2(b[0] * LOG2E, b[1] * LOG2E);
        qf[ks].w[3] = pk2(b[2] * LOG2E, b[3] * LOG2E);
    }
    if (ntile > 0) {
        writeV(0);
        __syncthreads();               // compiler drains vmcnt (async K) + lgkm before barrier
    }

    for (int t = 0; t < ntile; ++t) {
        const int bf = t & 1;
        const bool pf = (t + 1 < ntile);
        if (pf) { gloadK(bf ^ 1, (t + 1) * KVB); issueV((t + 1) * KVB); }   // into idle buffers

        // ---- S^T = K · Q^T (log2 units) ----
        f32x16 accs[2];
        accs[0] = z16; accs[1] = z16;
#pragma unroll
        for (int ks = 0; ks < 8; ++ks) {
#pragma unroll
            for (int n = 0; n < 2; ++n) {
                int row = n * 32 + q31;
                F16_8 kf;
                kf.u = *(const u16x8*)&K_lds[bf][(row * 128 + ks * 16 + hi * 8) ^ ((row & 7) << 3)];
                accs[n] = __builtin_amdgcn_mfma_f32_32x32x16_f16(kf.h, qf[ks].h, accs[n], 0, 0, 0);
            }
        }

        // ---- pad-mask: only the final partial tile ----
        if ((t == ntile - 1) && (count & 63)) {
#pragma unroll
            for (int n = 0; n < 2; ++n)
#pragma unroll
                for (int blk = 0; blk < 4; ++blk) {
                    f32x4 md = *(const f32x4*)&maskadd[n * 32 + blk * 8 + 4 * hi];
#pragma unroll
                    for (int r = 0; r < 4; ++r) accs[n][blk * 4 + r] += md[r];
                }
        }

        // ---- max: depth-5 tree ----
        float mx[16];
#pragma unroll
        for (int i = 0; i < 16; ++i) mx[i] = fmaxf(accs[0][i], accs[1][i]);
#pragma unroll
        for (int s = 8; s >= 1; s >>= 1)
#pragma unroll
            for (int i = 0; i < s; ++i) mx[i] = fmaxf(mx[i], mx[i + s]);
        float pmax = fmaxf(mx[0], __shfl_xor(mx[0], 32));

        // ---- online softmax, defer-max; threshold 8 nats = 11.54 log2-units ----
        if (!__all(pmax - mrun <= 11.5409f)) {
            float mnew = fmaxf(mrun, pmax);
            float sc = __builtin_amdgcn_exp2f(mrun - mnew);
#pragma unroll
            for (int dn = 0; dn < 4; ++dn)
#pragma unroll
                for (int i = 0; i < 16; ++i) acco[dn][i] *= sc;
            accl[0] *= sc;
            mrun = mnew;
        }

#pragma unroll
        for (int n = 0; n < 2; ++n)
#pragma unroll
            for (int i = 0; i < 16; ++i) accs[n][i] = __builtin_amdgcn_exp2f(accs[n][i] - mrun);

        // ---- P^T -> B-fragments via permlane32_swap ----
        F16_8 pa[4];
#pragma unroll
        for (int ks = 0; ks < 4; ++ks) {
            int n  = ks >> 1;
            int b4 = (ks & 1) * 8;
            uint32_t x0 = pk2(accs[n][b4 + 0], accs[n][b4 + 1]);
            uint32_t x1 = pk2(accs[n][b4 + 2], accs[n][b4 + 3]);
            uint32_t y0 = pk2(accs[n][b4 + 4], accs[n][b4 + 5]);
            uint32_t y1 = pk2(accs[n][b4 + 6], accs[n][b4 + 7]);
            asm volatile("v_permlane32_swap_b32 %0, %1" : "+v"(x0), "+v"(y0));
            asm volatile("v_permlane32_swap_b32 %0, %1" : "+v"(x1), "+v"(y1));
            pa[ks].w[0] = x0; pa[ks].w[1] = x1; pa[ks].w[2] = y0; pa[ks].w[3] = y1;
        }

        if (pf) writeV(bf ^ 1);                // idle buffer: no barrier needed before write

        // ---- O^T += V^T · P^T from VT_lds[bf] ----
#pragma unroll
        for (int dn = 0; dn < 4; ++dn) {
            int row = dn * 32 + q31;
#pragma unroll
            for (int ks = 0; ks < 4; ++ks) {
                F16_8 vf;
                vf.u = *(const u16x8*)&VT_lds[bf][row * 64 + ((ks * 16 + hi * 8) ^ ((row & 7) << 3))];
                acco[dn] = __builtin_amdgcn_mfma_f32_32x32x16_f16(vf.h, pa[ks].h, acco[dn], 0, 0, 0);
            }
        }
#pragma unroll
        for (int ks = 0; ks < 4; ++ks)
            accl = __builtin_amdgcn_mfma_f32_32x32x16_f16(ones.h, pa[ks].h, accl, 0, 0, 0);

        if (pf) __syncthreads();               // single barrier: t's reads done, t+1's stages visible
    }

    // ---- epilogue ----
    float lv   = accl[0];
    float linv = lv > 0.f ? 1.0f / lv : 0.f;   // count==0 -> O=0 (matches reference)
    float* orow = O + (qrow0 + q31) * Dd;
#pragma unroll
    for (int dn = 0; dn < 4; ++dn)
#pragma unroll
        for (int rg = 0; rg < 4; ++rg) {
            f32x4 o;
            o[0] = acco[dn][rg * 4 + 0] * linv;
            o[1] = acco[dn][rg * 4 + 1] * linv;
            o[2] = acco[dn][rg * 4 + 2] * linv;
            o[3] = acco[dn][rg * 4 + 3] * linv;
            *(f32x4*)(orow + dn * 32 + rg * 8 + 4 * hi) = o;
        }
}

// ---------------- fallback: verbatim R5 (used only if workspace missing) ----------------
__global__ __launch_bounds__(256) __attribute__((amdgpu_waves_per_eu(2, 2)))
void attn_fwd(const float* __restrict__ Q,
              const float* __restrict__ K,
              const float* __restrict__ V,
              const int* __restrict__ M,
              float* __restrict__ O) {
    __shared__ unsigned short K_lds[KVB * 128];
    __shared__ unsigned short VT_lds[128 * 64];
    __shared__ float maskadd[KVB];

    const int tid = threadIdx.x;
    const int w   = tid >> 6;
    const int l   = tid & 63;
    const int q31 = l & 31;
    const int hi  = l >> 5;

    const int bid   = blockIdx.x;
    const int batch = (bid & 7) * 4 + (bid >> 7);
    const int qtile = (bid >> 3) & 15;

    const size_t qrow0  = (size_t)batch * Ss + qtile * 128 + w * 32;
    const size_t kvbase = (size_t)batch * Ss * Dd;
    const size_t mbase  = (size_t)batch * Ss;

    const int krow = tid >> 4;
    const int kcol = (tid & 15) << 3;
    const int vi   = tid & 15;
    const int vk   = (tid >> 4) << 2;

    f32x4 ka[4], kb[4];
    f32x2 vv[4][4];
    int mld = 0;

    auto issueK = [&](int kv) {
#pragma unroll
        for (int it = 0; it < 4; ++it) {
            const float* s = K + kvbase + (size_t)(kv + krow + it * 16) * Dd + kcol;
            ka[it] = *(const f32x4*)s;
            kb[it] = *(const f32x4*)(s + 4);
        }
        if (tid < KVB) mld = M[mbase + kv + tid];
    };
    auto writeK = [&]() {
#pragma unroll
        for (int it = 0; it < 4; ++it) {
            int row = krow + it * 16;
            F16_8 t;
            t.w[0] = pk2(ka[it][0], ka[it][1]);
            t.w[1] = pk2(ka[it][2], ka[it][3]);
            t.w[2] = pk2(kb[it][0], kb[it][1]);
            t.w[3] = pk2(kb[it][2], kb[it][3]);
            *(u16x8*)&K_lds[(row * 128 + kcol) ^ ((row & 7) << 3)] = t.u;
        }
        if (tid < KVB) maskadd[tid] = mld ? 0.f : -1e30f;
    };
    auto issueV = [&](int kv) {
#pragma unroll
        for (int j = 0; j < 4; ++j)
#pragma unroll
            for (int ko = 0; ko < 4; ++ko)
                vv[j][ko] = *(const f32x2*)(V + kvbase + (size_t)(kv + vk + ko) * Dd + 2 * vi + 32 * j);
    };
    auto writeV = [&]() {
#pragma unroll
        for (int j = 0; j < 4; ++j)
#pragma unroll
            for (int p = 0; p < 2; ++p) {
                int row = 2 * vi + p + 32 * j;
                F16_4 t;
                t.w[0] = pk2(vv[j][0][p], vv[j][1][p]);
                t.w[1] = pk2(vv[j][2][p], vv[j][3][p]);
                *(u16x4*)&VT_lds[row * 64 + (vk ^ ((row & 7) << 3))] = t.u;
            }
    };

    F16_8 ones;
    {
        uint32_t ow = (q31 < 8) ? 0x3C003C00u : 0u;
        ones.w[0] = ow; ones.w[1] = ow; ones.w[2] = ow; ones.w[3] = ow;
    }

    const f32x16 z16 = {0,0,0,0,0,0,0,0,0,0,0,0,0,0,0,0};
    f32x16 acco[4];
#pragma unroll
    for (int dn = 0; dn < 4; ++dn) acco[dn] = z16;
    f32x16 accl = z16;
    float mrun = -1e4f;

    const float LOG2E = 1.44269504088896340736f;
    issueK(0); issueV(0);
    F16_8 qf[8];
#pragma unroll
    for (int ks = 0; ks < 8; ++ks) {
        const float* s = Q + (qrow0 + q31) * Dd + ks * 16 + hi * 8;
        f32x4 a = *(const f32x4*)s;
        f32x4 b = *(const f32x4*)(s + 4);
        qf[ks].w[0] = pk2(a[0] * LOG2E, a[1] * LOG2E);
        qf[ks].w[1] = pk2(a[2] * LOG2E, a[3] * LOG2E);
        qf[ks].w[2] = pk2(b[0] * LOG2E, b[1] * LOG2E);
        qf[ks].w[3] = pk2(b[2] * LOG2E, b[3] * LOG2E);
    }
    writeK(); writeV();
    __syncthreads();

    for (int t = 0; t < NIT; ++t) {
        if (t < NIT - 1) issueK((t + 1) * KVB);

        f32x16 accs[2];
        accs[0] = z16; accs[1] = z16;
#pragma unroll
        for (int ks = 0; ks < 8; ++ks) {
#pragma unroll
            for (int n = 0; n < 2; ++n) {
                int row = n * 32 + q31;
                F16_8 kf;
                kf.u = *(const u16x8*)&K_lds[(row * 128 + ks * 16 + hi * 8) ^ ((row & 7) << 3)];
                accs[n] = __builtin_amdgcn_mfma_f32_32x32x16_f16(kf.h, qf[ks].h, accs[n], 0, 0, 0);
            }
        }

#pragma unroll
        for (int n = 0; n < 2; ++n)
#pragma unroll
            for (int blk = 0; blk < 4; ++blk) {
                f32x4 md = *(const f32x4*)&maskadd[n * 32 + blk * 8 + 4 * hi];
#pragma unroll
                for (int r = 0; r < 4; ++r) accs[n][blk * 4 + r] += md[r];
            }

        float mx[16];
#pragma unroll
        for (int i = 0; i < 16; ++i) mx[i] = fmaxf(accs[0][i], accs[1][i]);
#pragma unroll
        for (int s = 8; s >= 1; s >>= 1)
#pragma unroll
            for (int i = 0; i < s; ++i) mx[i] = fmaxf(mx[i], mx[i + s]);
        float pmax = fmaxf(mx[0], __shfl_xor(mx[0], 32));

        if (!__all(pmax - mrun <= 11.5409f)) {
            float mnew = fmaxf(mrun, pmax);
            float sc = __builtin_amdgcn_exp2f(mrun - mnew);
#pragma unroll
            for (int dn = 0; dn < 4; ++dn)
#pragma unroll
                for (int i = 0; i < 16; ++i) acco[dn][i] *= sc;
            accl[0] *= sc;
            mrun = mnew;
        }

#pragma unroll
        for (int n = 0; n < 2; ++n)
#pragma unroll
            for (int i = 0; i < 16; ++i) accs[n][i] = __builtin_amdgcn_exp2f(accs[n][i] - mrun);

        F16_8 pa[4];
#pragma unroll
        for (int ks = 0; ks < 4; ++ks) {
            int n  = ks >> 1;
            int b4 = (ks & 1) * 8;
            uint32_t x0 = pk2(accs[n][b4 + 0], accs[n][b4 + 1]);
            uint32_t x1 = pk2(accs[n][b4 + 2], accs[n][b4 + 3]);
            uint32_t y0 = pk2(accs[n][b4 + 4], accs[n][b4 + 5]);
            uint32_t y1 = pk2(accs[n][b4 + 6], accs[n][b4 + 7]);
            asm volatile("v_permlane32_swap_b32 %0, %1" : "+v"(x0), "+v"(y0));
            asm volatile("v_permlane32_swap_b32 %0, %1" : "+v"(x1), "+v"(y1));
            pa[ks].w[0] = x0; pa[ks].w[1] = x1; pa[ks].w[2] = y0; pa[ks].w[3] = y1;
        }

        __syncthreads();
        if (t < NIT - 1) { writeK(); issueV((t + 1) * KVB); }

#pragma unroll
        for (int dn = 0; dn < 4; ++dn) {
            int row = dn * 32 + q31;
#pragma unroll
            for (int ks = 0; ks < 4; ++ks) {
                F16_8 vf;
                vf.u = *(const u16x8*)&VT_lds[row * 64 + ((ks * 16 + hi * 8) ^ ((row & 7) << 3))];
                acco[dn] = __builtin_amdgcn_mfma_f32_32x32x16_f16(vf.h, pa[ks].h, acco[dn], 0, 0, 0);
            }
        }
#pragma unroll
        for (int ks = 0; ks < 4; ++ks)
            accl = __builtin_amdgcn_mfma_f32_32x32x16_f16(ones.h, pa[ks].h, accl, 0, 0, 0);

        __syncthreads();
        if (t < NIT - 1) writeV();
    }

    float lv   = accl[0];
    float linv = lv > 0.f ? 1.0f / lv : 0.f;
    float* orow = O + (qrow0 + q31) * Dd;
#pragma unroll
    for (int dn = 0; dn < 4; ++dn)
#pragma unroll
        for (int rg = 0; rg < 4; ++rg) {
            f32x4 o;
            o[0] = acco[dn][rg * 4 + 0] * linv;
            o[1] = acco[dn][rg * 4 + 1] * linv;
            o[2] = acco[dn][rg * 4 + 2] * linv;
            o[3] = acco[dn][rg * 4 + 3] * linv;
            *(f32x4*)(orow + dn * 32 + rg * 8 + 4 * hi) = o;
        }
}

extern "C" void kernel_launch(void* const* d_in, const int* in_sizes, int n_in,
                              void* d_out, int out_size, void* d_ws, size_t ws_size,
                              hipStream_t stream) {
    const float* Q = (const float*)d_in[0];
    const float* K = (const float*)d_in[1];
    const float* V = (const float*)d_in[2];
    const int*   M = (const int*)d_in[3];
    float* O = (float*)d_out;

    const size_t nKV  = (size_t)Bb * Ss * Dd;                  // elems per compacted array
    const size_t need = nKV * 2 * 2 + (size_t)Bb * 4;          // Kc+Vc fp16 + CNT

    if (d_ws != nullptr && ws_size >= need) {
        unsigned short* Kc  = (unsigned short*)d_ws;
        unsigned short* Vc  = Kc + nKV;
        int*            CNT = (int*)(Vc + nKV);
        attn_prep<<<dim3(Bb * 32), dim3(256), 0, stream>>>(K, V, M, Kc, Vc, CNT);
        attn_fwd_d<<<dim3(Bb * (Ss / 128)), dim3(256), 0, stream>>>(Q, Kc, Vc, CNT, O);
    } else {
        attn_fwd<<<dim3(Bb * (Ss / 128)), dim3(256), 0, stream>>>(Q, K, V, M, O);
    }
}

// Round 10
// 65.718 us; speedup vs baseline: 1.9897x; 1.0592x over previous
//
#include <hip/hip_runtime.h>
#include <stdint.h>

#define Bb 32
#define Ss 2048
#define Dd 128
#define KVB 64
#define NIT (Ss / KVB)   // 32

typedef __attribute__((ext_vector_type(2))) float f32x2;
typedef __attribute__((ext_vector_type(4))) float f32x4;
typedef __attribute__((ext_vector_type(16))) float f32x16;
typedef __attribute__((ext_vector_type(8))) _Float16 f16x8;
typedef __attribute__((ext_vector_type(2))) __fp16 fp16x2;
typedef __attribute__((ext_vector_type(8))) unsigned short u16x8;
typedef __attribute__((ext_vector_type(4))) unsigned short u16x4;

union F16_8 { u16x8 u; uint32_t w[4]; f16x8 h; };
union F16_4 { u16x4 u; uint32_t w[2]; };

__device__ __forceinline__ uint32_t pk2(float a, float b) {   // packed f32->f16 RTZ
    union { fp16x2 h; uint32_t u; } v;
    v.h = __builtin_amdgcn_cvt_pkrtz(a, b);
    return v.u;
}

// ---------------------------------------------------------------------------
// prep: per-batch mask scan + gather-compact K,V into FRAGMENT-MAJOR fp16.
//   Kf[b][t][ks 0..7][n 0..1][lane 0..63] : 8 u16 = K[key=n*32+(l&31)][d=ks*16+(l>>5)*8 ..+8]
//   Vf[b][t][dn 0..3][ks 0..3][lane 0..63]: 8 u16 = V[key=ks*16+(l>>5)*8+jj][d=dn*32+(l&31)]
// One tile = 8192 u16 = 16 KB for each array. Pad fragments zeroed.
// Grid XCD-aligned: batch b's blocks run on XCD b>>2 (same as main's consumers).
// ---------------------------------------------------------------------------
__global__ __launch_bounds__(256)
void attn_prep(const float* __restrict__ K, const float* __restrict__ V,
               const int* __restrict__ M,
               unsigned short* __restrict__ Kf, unsigned short* __restrict__ Vf,
               int* __restrict__ CNT) {
    __shared__ int scan_s[256];
    __shared__ unsigned short idx_l[Ss];          // 4 KB
    __shared__ unsigned short vt[KVB * 128];      // 16 KB, [key][d] fp16 tile

    const int x = blockIdx.x;
    const int b     = ((x & 7) << 2) | ((x >> 3) & 3);   // XCD = x%8 = b>>2
    const int chunk = x >> 5;
    const int tid = threadIdx.x;

    // ---- redundant per-block scan of this batch's mask ----
    const int* m = M + (size_t)b * Ss + tid * 8;
    int loc[8]; int csum = 0;
    {
        int4 a = *(const int4*)m;
        int4 c = *(const int4*)(m + 4);
        loc[0] = (a.x != 0); loc[1] = (a.y != 0); loc[2] = (a.z != 0); loc[3] = (a.w != 0);
        loc[4] = (c.x != 0); loc[5] = (c.y != 0); loc[6] = (c.z != 0); loc[7] = (c.w != 0);
#pragma unroll
        for (int j = 0; j < 8; ++j) csum += loc[j];
    }
    scan_s[tid] = csum;
    __syncthreads();
    for (int off = 1; off < 256; off <<= 1) {     // Hillis-Steele inclusive scan
        int v = scan_s[tid];
        int u = (tid >= off) ? scan_s[tid - off] : 0;
        __syncthreads();
        scan_s[tid] = v + u;
        __syncthreads();
    }
    const int count = scan_s[255];
    {
        int base = scan_s[tid] - csum;            // exclusive prefix
#pragma unroll
        for (int j = 0; j < 8; ++j)
            if (loc[j]) idx_l[base++] = (unsigned short)(tid * 8 + j);
    }
    __syncthreads();
    if (chunk == 0 && tid == 0) CNT[b] = count;

    const int ntile = (count + 63) >> 6;
    if (chunk >= ntile) return;                   // block-uniform exit

    const int kb = chunk * 64;
    const size_t gbase = (size_t)b * Ss * Dd;
    const size_t fbase = ((size_t)b * 32 + chunk) * 8192;   // u16 units

    // ---- K fragments: direct row-gather ----
#pragma unroll
    for (int j = 0; j < 4; ++j) {
        const int o  = tid + 256 * j;             // 0..1023
        const int l  = o & 63;
        const int fn = o >> 6;                    // 0..15
        const int ks = fn >> 1, n = fn & 1;
        const int s  = kb + n * 32 + (l & 31);
        const int d0 = ks * 16 + (l >> 5) * 8;
        F16_8 t;
        if (s < count) {
            const float* sp = K + gbase + (size_t)idx_l[s] * Dd + d0;
            f32x4 xv = *(const f32x4*)sp;
            f32x4 yv = *(const f32x4*)(sp + 4);
            t.w[0] = pk2(xv[0], xv[1]); t.w[1] = pk2(xv[2], xv[3]);
            t.w[2] = pk2(yv[0], yv[1]); t.w[3] = pk2(yv[2], yv[3]);
        } else {
            t.w[0] = 0u; t.w[1] = 0u; t.w[2] = 0u; t.w[3] = 0u;
        }
        *(u16x8*)(Kf + fbase + (size_t)o * 8) = t.u;
    }

    // ---- stage V tile [key][d] fp16 in LDS ----
    {
        const int rsub = tid >> 4;
        const int colh = (tid & 15) * 8;
#pragma unroll
        for (int it = 0; it < 4; ++it) {
            const int row = rsub + it * 16;
            const int s   = kb + row;
            F16_8 t;
            if (s < count) {
                const float* sp = V + gbase + (size_t)idx_l[s] * Dd + colh;
                f32x4 xv = *(const f32x4*)sp;
                f32x4 yv = *(const f32x4*)(sp + 4);
                t.w[0] = pk2(xv[0], xv[1]); t.w[1] = pk2(xv[2], xv[3]);
                t.w[2] = pk2(yv[0], yv[1]); t.w[3] = pk2(yv[2], yv[3]);
            } else {
                t.w[0] = 0u; t.w[1] = 0u; t.w[2] = 0u; t.w[3] = 0u;
            }
            *(u16x8*)&vt[row * 128 + colh] = t.u;
        }
    }
    __syncthreads();

    // ---- V fragments: transpose-read from vt ----
#pragma unroll
    for (int j = 0; j < 4; ++j) {
        const int o  = tid + 256 * j;
        const int l  = o & 63;
        const int fn = o >> 6;
        const int dn = fn >> 2, ks = fn & 3;
        const int d  = dn * 32 + (l & 31);
        const int k0 = ks * 16 + (l >> 5) * 8;
        u16x8 t;
#pragma unroll
        for (int jj = 0; jj < 8; ++jj) t[jj] = vt[(k0 + jj) * 128 + d];
        *(u16x8*)(Vf + fbase + (size_t)o * 8) = t;
    }
}

// ---------------------------------------------------------------------------
// main: fragment-major K/V, linear async global_load_lds double-buffer,
// ONE barrier per tile, conflict-free ds_read_b128 (lane*16 + imm), no repack.
// ---------------------------------------------------------------------------
__global__ __launch_bounds__(256) __attribute__((amdgpu_waves_per_eu(2, 2)))
void attn_fwd_f(const float* __restrict__ Q,
                const unsigned short* __restrict__ Kf,
                const unsigned short* __restrict__ Vf,
                const int* __restrict__ CNT,
                float* __restrict__ O) {
    __shared__ unsigned short K_lds[2][8192];   // 2x16 KB, fragment-major
    __shared__ unsigned short V_lds[2][8192];   // 2x16 KB, fragment-major

    const int tid = threadIdx.x;
    const int w   = tid >> 6;
    const int l   = tid & 63;
    const int q31 = l & 31;
    const int hi  = l >> 5;

    const int bid   = blockIdx.x;
    const int batch = (bid & 7) * 4 + (bid >> 7);   // XCD-aware, bijective; XCD = batch>>2
    const int qtile = (bid >> 3) & 15;

    const size_t qrow0 = (size_t)batch * Ss + qtile * 128 + w * 32;
    const size_t kfb   = (size_t)batch * 32 * 8192;   // u16 units

    const int count = CNT[batch];
    const int ntile = (count + KVB - 1) >> 6;

    // async tile stage: linear dest, linear per-lane source (no swizzle anywhere)
    auto gload = [&](int kv_t, const unsigned short* base, unsigned short (&dstb)[8192]) {
#pragma unroll
        for (int it = 0; it < 4; ++it) {
            const int ob = it * 4096 + w * 1024;                      // byte offset, wave-uniform
            const unsigned short* src = base + (size_t)kv_t * 8192 + (ob >> 1) + l * 8;
            void* dst = (char*)&dstb[0] + ob;
            __builtin_amdgcn_global_load_lds(
                (const __attribute__((address_space(1))) uint32_t*)src,
                (__attribute__((address_space(3))) uint32_t*)dst, 16, 0, 0);
        }
    };

    // ones A-fragment (rows 0..7 = 1.0) for MFMA-computed l
    F16_8 ones;
    {
        uint32_t ow = (q31 < 8) ? 0x3C003C00u : 0u;
        ones.w[0] = ow; ones.w[1] = ow; ones.w[2] = ow; ones.w[3] = ow;
    }

    const f32x16 z16 = {0,0,0,0,0,0,0,0,0,0,0,0,0,0,0,0};
    f32x16 acco[4];
#pragma unroll
    for (int dn = 0; dn < 4; ++dn) acco[dn] = z16;
    f32x16 accl = z16;
    float mrun = -1e4f;

    // ---- prologue ----
    const float LOG2E = 1.44269504088896340736f;
    if (ntile > 0) { gload(0, Kf + kfb, K_lds[0]); gload(0, Vf + kfb, V_lds[0]); }
    F16_8 qf[8];
#pragma unroll
    for (int ks = 0; ks < 8; ++ks) {
        const float* s = Q + (qrow0 + q31) * Dd + ks * 16 + hi * 8;
        f32x4 a = *(const f32x4*)s;
        f32x4 b = *(const f32x4*)(s + 4);
        qf[ks].w[0] = pk2(a[0] * LOG2E, a[1] * LOG2E);
        qf[ks].w[1] = pk2(a[2] * LOG2E, a[3] * LOG2E);
        qf[ks].w[2] = pk2(b[0] * LOG2E, b[1] * LOG2E);
        qf[ks].w[3] = pk2(b[2] * LOG2E, b[3] * LOG2E);
    }
    if (ntile > 0) __syncthreads();               // drains async stage of tile 0

    const int lb = l * 16;                        // per-lane LDS fragment byte base

    for (int t = 0; t < ntile; ++t) {
        const int bf = t & 1;
        const bool pf = (t + 1 < ntile);
        if (pf) {                                  // prefetch next tile into idle buffers
            gload(t + 1, Kf + kfb, K_lds[bf ^ 1]);
            gload(t + 1, Vf + kfb, V_lds[bf ^ 1]);
        }

        // ---- S^T = K · Q^T (log2 units): conflict-free consecutive ds_read_b128 ----
        f32x16 accs[2];
        accs[0] = z16; accs[1] = z16;
        const char* kl = (const char*)&K_lds[bf][0];
#pragma unroll
        for (int ks = 0; ks < 8; ++ks) {
#pragma unroll
            for (int n = 0; n < 2; ++n) {
                F16_8 kf;
                kf.u = *(const u16x8*)(kl + (ks * 2 + n) * 1024 + lb);
                accs[n] = __builtin_amdgcn_mfma_f32_32x32x16_f16(kf.h, qf[ks].h, accs[n], 0, 0, 0);
            }
        }

        // ---- pad-mask in registers: only the final partial tile ----
        if ((t == ntile - 1) && (count & 63)) {
            const int rem = count - t * 64;       // 1..63
#pragma unroll
            for (int n = 0; n < 2; ++n)
#pragma unroll
                for (int i = 0; i < 16; ++i) {
                    const int key = n * 32 + (i >> 2) * 8 + 4 * hi + (i & 3);
                    accs[n][i] = (key < rem) ? accs[n][i] : -1e30f;
                }
        }

        // ---- max: depth-5 tree ----
        float mx[16];
#pragma unroll
        for (int i = 0; i < 16; ++i) mx[i] = fmaxf(accs[0][i], accs[1][i]);
#pragma unroll
        for (int s = 8; s >= 1; s >>= 1)
#pragma unroll
            for (int i = 0; i < s; ++i) mx[i] = fmaxf(mx[i], mx[i + s]);
        float pmax = fmaxf(mx[0], __shfl_xor(mx[0], 32));

        // ---- online softmax, defer-max; threshold 8 nats = 11.54 log2-units ----
        if (!__all(pmax - mrun <= 11.5409f)) {
            float mnew = fmaxf(mrun, pmax);
            float sc = __builtin_amdgcn_exp2f(mrun - mnew);
#pragma unroll
            for (int dn = 0; dn < 4; ++dn)
#pragma unroll
                for (int i = 0; i < 16; ++i) acco[dn][i] *= sc;
            accl[0] *= sc;
            mrun = mnew;
        }

#pragma unroll
        for (int n = 0; n < 2; ++n)
#pragma unroll
            for (int i = 0; i < 16; ++i) accs[n][i] = __builtin_amdgcn_exp2f(accs[n][i] - mrun);

        // ---- P^T -> B-fragments via permlane32_swap ----
        F16_8 pa[4];
#pragma unroll
        for (int ks = 0; ks < 4; ++ks) {
            int n  = ks >> 1;
            int b4 = (ks & 1) * 8;
            uint32_t x0 = pk2(accs[n][b4 + 0], accs[n][b4 + 1]);
            uint32_t x1 = pk2(accs[n][b4 + 2], accs[n][b4 + 3]);
            uint32_t y0 = pk2(accs[n][b4 + 4], accs[n][b4 + 5]);
            uint32_t y1 = pk2(accs[n][b4 + 6], accs[n][b4 + 7]);
            asm volatile("v_permlane32_swap_b32 %0, %1" : "+v"(x0), "+v"(y0));
            asm volatile("v_permlane32_swap_b32 %0, %1" : "+v"(x1), "+v"(y1));
            pa[ks].w[0] = x0; pa[ks].w[1] = x1; pa[ks].w[2] = y0; pa[ks].w[3] = y1;
        }

        // ---- O^T += V^T · P^T: conflict-free fragment reads ----
        const char* vl = (const char*)&V_lds[bf][0];
#pragma unroll
        for (int dn = 0; dn < 4; ++dn) {
#pragma unroll
            for (int ks = 0; ks < 4; ++ks) {
                F16_8 vf;
                vf.u = *(const u16x8*)(vl + (dn * 4 + ks) * 1024 + lb);
                acco[dn] = __builtin_amdgcn_mfma_f32_32x32x16_f16(vf.h, pa[ks].h, acco[dn], 0, 0, 0);
            }
        }
#pragma unroll
        for (int ks = 0; ks < 4; ++ks)
            accl = __builtin_amdgcn_mfma_f32_32x32x16_f16(ones.h, pa[ks].h, accl, 0, 0, 0);

        if (pf) __syncthreads();               // single barrier: t's reads done, t+1's stage visible
    }

    // ---- epilogue ----
    float lv   = accl[0];
    float linv = lv > 0.f ? 1.0f / lv : 0.f;   // count==0 -> O=0 (matches reference)
    float* orow = O + (qrow0 + q31) * Dd;
#pragma unroll
    for (int dn = 0; dn < 4; ++dn)
#pragma unroll
        for (int rg = 0; rg < 4; ++rg) {
            f32x4 o;
            o[0] = acco[dn][rg * 4 + 0] * linv;
            o[1] = acco[dn][rg * 4 + 1] * linv;
            o[2] = acco[dn][rg * 4 + 2] * linv;
            o[3] = acco[dn][rg * 4 + 3] * linv;
            *(f32x4*)(orow + dn * 32 + rg * 8 + 4 * hi) = o;
        }
}

// ---------------- fallback: verbatim R5 (used only if workspace missing) ----------------
__global__ __launch_bounds__(256) __attribute__((amdgpu_waves_per_eu(2, 2)))
void attn_fwd(const float* __restrict__ Q,
              const float* __restrict__ K,
              const float* __restrict__ V,
              const int* __restrict__ M,
              float* __restrict__ O) {
    __shared__ unsigned short K_lds[KVB * 128];
    __shared__ unsigned short VT_lds[128 * 64];
    __shared__ float maskadd[KVB];

    const int tid = threadIdx.x;
    const int w   = tid >> 6;
    const int l   = tid & 63;
    const int q31 = l & 31;
    const int hi  = l >> 5;

    const int bid   = blockIdx.x;
    const int batch = (bid & 7) * 4 + (bid >> 7);
    const int qtile = (bid >> 3) & 15;

    const size_t qrow0  = (size_t)batch * Ss + qtile * 128 + w * 32;
    const size_t kvbase = (size_t)batch * Ss * Dd;
    const size_t mbase  = (size_t)batch * Ss;

    const int krow = tid >> 4;
    const int kcol = (tid & 15) << 3;
    const int vi   = tid & 15;
    const int vk   = (tid >> 4) << 2;

    f32x4 ka[4], kb[4];
    f32x2 vv[4][4];
    int mld = 0;

    auto issueK = [&](int kv) {
#pragma unroll
        for (int it = 0; it < 4; ++it) {
            const float* s = K + kvbase + (size_t)(kv + krow + it * 16) * Dd + kcol;
            ka[it] = *(const f32x4*)s;
            kb[it] = *(const f32x4*)(s + 4);
        }
        if (tid < KVB) mld = M[mbase + kv + tid];
    };
    auto writeK = [&]() {
#pragma unroll
        for (int it = 0; it < 4; ++it) {
            int row = krow + it * 16;
            F16_8 t;
            t.w[0] = pk2(ka[it][0], ka[it][1]);
            t.w[1] = pk2(ka[it][2], ka[it][3]);
            t.w[2] = pk2(kb[it][0], kb[it][1]);
            t.w[3] = pk2(kb[it][2], kb[it][3]);
            *(u16x8*)&K_lds[(row * 128 + kcol) ^ ((row & 7) << 3)] = t.u;
        }
        if (tid < KVB) maskadd[tid] = mld ? 0.f : -1e30f;
    };
    auto issueV = [&](int kv) {
#pragma unroll
        for (int j = 0; j < 4; ++j)
#pragma unroll
            for (int ko = 0; ko < 4; ++ko)
                vv[j][ko] = *(const f32x2*)(V + kvbase + (size_t)(kv + vk + ko) * Dd + 2 * vi + 32 * j);
    };
    auto writeV = [&]() {
#pragma unroll
        for (int j = 0; j < 4; ++j)
#pragma unroll
            for (int p = 0; p < 2; ++p) {
                int row = 2 * vi + p + 32 * j;
                F16_4 t;
                t.w[0] = pk2(vv[j][0][p], vv[j][1][p]);
                t.w[1] = pk2(vv[j][2][p], vv[j][3][p]);
                *(u16x4*)&VT_lds[row * 64 + (vk ^ ((row & 7) << 3))] = t.u;
            }
    };

    F16_8 ones;
    {
        uint32_t ow = (q31 < 8) ? 0x3C003C00u : 0u;
        ones.w[0] = ow; ones.w[1] = ow; ones.w[2] = ow; ones.w[3] = ow;
    }

    const f32x16 z16 = {0,0,0,0,0,0,0,0,0,0,0,0,0,0,0,0};
    f32x16 acco[4];
#pragma unroll
    for (int dn = 0; dn < 4; ++dn) acco[dn] = z16;
    f32x16 accl = z16;
    float mrun = -1e4f;

    const float LOG2E = 1.44269504088896340736f;
    issueK(0); issueV(0);
    F16_8 qf[8];
#pragma unroll
    for (int ks = 0; ks < 8; ++ks) {
        const float* s = Q + (qrow0 + q31) * Dd + ks * 16 + hi * 8;
        f32x4 a = *(const f32x4*)s;
        f32x4 b = *(const f32x4*)(s + 4);
        qf[ks].w[0] = pk2(a[0] * LOG2E, a[1] * LOG2E);
        qf[ks].w[1] = pk2(a[2] * LOG2E, a[3] * LOG2E);
        qf[ks].w[2] = pk2(b[0] * LOG2E, b[1] * LOG2E);
        qf[ks].w[3] = pk2(b[2] * LOG2E, b[3] * LOG2E);
    }
    writeK(); writeV();
    __syncthreads();

    for (int t = 0; t < NIT; ++t) {
        if (t < NIT - 1) issueK((t + 1) * KVB);

        f32x16 accs[2];
        accs[0] = z16; accs[1] = z16;
#pragma unroll
        for (int ks = 0; ks < 8; ++ks) {
#pragma unroll
            for (int n = 0; n < 2; ++n) {
                int row = n * 32 + q31;
                F16_8 kf;
                kf.u = *(const u16x8*)&K_lds[(row * 128 + ks * 16 + hi * 8) ^ ((row & 7) << 3)];
                accs[n] = __builtin_amdgcn_mfma_f32_32x32x16_f16(kf.h, qf[ks].h, accs[n], 0, 0, 0);
            }
        }

#pragma unroll
        for (int n = 0; n < 2; ++n)
#pragma unroll
            for (int blk = 0; blk < 4; ++blk) {
                f32x4 md = *(const f32x4*)&maskadd[n * 32 + blk * 8 + 4 * hi];
#pragma unroll
                for (int r = 0; r < 4; ++r) accs[n][blk * 4 + r] += md[r];
            }

        float mx[16];
#pragma unroll
        for (int i = 0; i < 16; ++i) mx[i] = fmaxf(accs[0][i], accs[1][i]);
#pragma unroll
        for (int s = 8; s >= 1; s >>= 1)
#pragma unroll
            for (int i = 0; i < s; ++i) mx[i] = fmaxf(mx[i], mx[i + s]);
        float pmax = fmaxf(mx[0], __shfl_xor(mx[0], 32));

        if (!__all(pmax - mrun <= 11.5409f)) {
            float mnew = fmaxf(mrun, pmax);
            float sc = __builtin_amdgcn_exp2f(mrun - mnew);
#pragma unroll
            for (int dn = 0; dn < 4; ++dn)
#pragma unroll
                for (int i = 0; i < 16; ++i) acco[dn][i] *= sc;
            accl[0] *= sc;
            mrun = mnew;
        }

#pragma unroll
        for (int n = 0; n < 2; ++n)
#pragma unroll
            for (int i = 0; i < 16; ++i) accs[n][i] = __builtin_amdgcn_exp2f(accs[n][i] - mrun);

        F16_8 pa[4];
#pragma unroll
        for (int ks = 0; ks < 4; ++ks) {
            int n  = ks >> 1;
            int b4 = (ks & 1) * 8;
            uint32_t x0 = pk2(accs[n][b4 + 0], accs[n][b4 + 1]);
            uint32_t x1 = pk2(accs[n][b4 + 2], accs[n][b4 + 3]);
            uint32_t y0 = pk2(accs[n][b4 + 4], accs[n][b4 + 5]);
            uint32_t y1 = pk2(accs[n][b4 + 6], accs[n][b4 + 7]);
            asm volatile("v_permlane32_swap_b32 %0, %1" : "+v"(x0), "+v"(y0));
            asm volatile("v_permlane32_swap_b32 %0, %1" : "+v"(x1), "+v"(y1));
            pa[ks].w[0] = x0; pa[ks].w[1] = x1; pa[ks].w[2] = y0; pa[ks].w[3] = y1;
        }

        __syncthreads();
        if (t < NIT - 1) { writeK(); issueV((t + 1) * KVB); }

#pragma unroll
        for (int dn = 0; dn < 4; ++dn) {
            int row = dn * 32 + q31;
#pragma unroll
            for (int ks = 0; ks < 4; ++ks) {
                F16_8 vf;
                vf.u = *(const u16x8*)&VT_lds[row * 64 + ((ks * 16 + hi * 8) ^ ((row & 7) << 3))];
                acco[dn] = __builtin_amdgcn_mfma_f32_32x32x16_f16(vf.h, pa[ks].h, acco[dn], 0, 0, 0);
            }
        }
#pragma unroll
        for (int ks = 0; ks < 4; ++ks)
            accl = __builtin_amdgcn_mfma_f32_32x32x16_f16(ones.h, pa[ks].h, accl, 0, 0, 0);

        __syncthreads();
        if (t < NIT - 1) writeV();
    }

    float lv   = accl[0];
    float linv = lv > 0.f ? 1.0f / lv : 0.f;
    float* orow = O + (qrow0 + q31) * Dd;
#pragma unroll
    for (int dn = 0; dn < 4; ++dn)
#pragma unroll
        for (int rg = 0; rg < 4; ++rg) {
            f32x4 o;
            o[0] = acco[dn][rg * 4 + 0] * linv;
            o[1] = acco[dn][rg * 4 + 1] * linv;
            o[2] = acco[dn][rg * 4 + 2] * linv;
            o[3] = acco[dn][rg * 4 + 3] * linv;
            *(f32x4*)(orow + dn * 32 + rg * 8 + 4 * hi) = o;
        }
}

extern "C" void kernel_launch(void* const* d_in, const int* in_sizes, int n_in,
                              void* d_out, int out_size, void* d_ws, size_t ws_size,
                              hipStream_t stream) {
    const float* Q = (const float*)d_in[0];
    const float* K = (const float*)d_in[1];
    const float* V = (const float*)d_in[2];
    const int*   M = (const int*)d_in[3];
    float* O = (float*)d_out;

    const size_t nF   = (size_t)Bb * 32 * 8192;                // u16 per fragment array
    const size_t need = nF * 2 * 2 + (size_t)Bb * 4;           // Kf+Vf fp16 + CNT

    if (d_ws != nullptr && ws_size >= need) {
        unsigned short* Kf  = (unsigned short*)d_ws;
        unsigned short* Vf  = Kf + nF;
        int*            CNT = (int*)(Vf + nF);
        attn_prep<<<dim3(Bb * 32), dim3(256), 0, stream>>>(K, V, M, Kf, Vf, CNT);
        attn_fwd_f<<<dim3(Bb * (Ss / 128)), dim3(256), 0, stream>>>(Q, Kf, Vf, CNT, O);
    } else {
        attn_fwd<<<dim3(Bb * (Ss / 128)), dim3(256), 0, stream>>>(Q, K, V, M, O);
    }
}